// Round 1
// baseline (3438.025 us; speedup 1.0000x reference)
//
#include <hip/hip_runtime.h>

#define NN 40000
#define NE 320000
#define HD 64
#define DC 16
#define TT 4

// ---------------- embedding: h = inputs @ W_emb  [N,16]@[16,64] ----------------
__global__ void emb_kernel(const float* __restrict__ x, const float* __restrict__ W,
                           float* __restrict__ h) {
    int i = blockIdx.x * blockDim.x + threadIdx.x;
    if (i >= NN * HD) return;
    int n = i >> 6, j = i & 63;
    float acc = 0.f;
#pragma unroll
    for (int k = 0; k < 16; ++k) acc = fmaf(x[n * 16 + k], W[k * 64 + j], acc);
    h[i] = acc;
}

// -------- gather e_feats[:, :, t] ([E,8,T] strided) into contiguous [E,8] --------
__global__ void gather_ef_kernel(const float* __restrict__ ef, int t, float* __restrict__ out) {
    int i = blockIdx.x * blockDim.x + threadIdx.x;
    if (i < NE * 8) out[i] = ef[i * 4 + t];
}

// ---- Wfold[k][j] = Wp_e[0][k][j] + Wp_e[0][k+8][j]  (folds tile(ef,(1,2))) ----
__global__ void wfold_kernel(const float* __restrict__ We, float* __restrict__ Wf) {
    int i = threadIdx.x;
    if (i < 128) Wf[i] = We[i] + We[i + 128];
}

// ---- node transform, 64-wide out: A = X1@Whs(+X2@Whs[64:]) + rain*Wr, B = X1@Whd(+...)
// Whs/Whd row-major [64+d2, 64]; wave per node, lane = out feature
__global__ void node_ab_kernel(const float* __restrict__ X1,
                               const float* __restrict__ X2, int d2,
                               const float* __restrict__ Whs, const float* __restrict__ Whd,
                               const float* __restrict__ rain, int rstride,
                               const float* __restrict__ Wr,
                               float* __restrict__ A, float* __restrict__ B) {
    extern __shared__ float sW[];
    int dtot = 64 + d2;
    float* sWs = sW;
    float* sWd = sW + dtot * 64;
    for (int i = threadIdx.x; i < dtot * 64; i += blockDim.x) {
        sWs[i] = Whs[i];
        sWd[i] = Whd[i];
    }
    __syncthreads();
    int lane = threadIdx.x & 63;
    int wid = (blockIdx.x * blockDim.x + threadIdx.x) >> 6;
    int nw = (gridDim.x * blockDim.x) >> 6;
    for (int n = wid; n < NN; n += nw) {
        float a = rain[n * rstride] * Wr[lane];
        float b = 0.f;
        float xv = X1[n * 64 + lane];
#pragma unroll
        for (int k = 0; k < 64; ++k) {
            float xk = __shfl(xv, k);
            a = fmaf(xk, sWs[k * 64 + lane], a);
            b = fmaf(xk, sWd[k * 64 + lane], b);
        }
        if (d2) {
            float xv2 = (lane < 16) ? X2[n * 16 + lane] : 0.f;
#pragma unroll
            for (int k = 0; k < 16; ++k) {
                float xk = __shfl(xv2, k);
                a = fmaf(xk, sWs[(64 + k) * 64 + lane], a);
                b = fmaf(xk, sWd[(64 + k) * 64 + lane], b);
            }
        }
        A[n * 64 + lane] = a;
        B[n * 64 + lane] = b;
    }
}

// ---- node transform, 16-wide out (prop layers). Wave handles 4 nodes. ----
__global__ void node_ab16_kernel(const float* __restrict__ h,
                                 const float* __restrict__ Whs, const float* __restrict__ Whd,
                                 const float* __restrict__ rain, int rstride,
                                 const float* __restrict__ Wr,
                                 float* __restrict__ Ap, float* __restrict__ Bp) {
    __shared__ float sWs[64 * 16], sWd[64 * 16];
    for (int i = threadIdx.x; i < 1024; i += blockDim.x) {
        sWs[i] = Whs[i];
        sWd[i] = Whd[i];
    }
    __syncthreads();
    int lane = threadIdx.x & 63;
    int g = lane >> 4, j = lane & 15;
    int wid = (blockIdx.x * blockDim.x + threadIdx.x) >> 6;
    int nw = (gridDim.x * blockDim.x) >> 6;
    for (int n4 = wid; n4 < NN / 4; n4 += nw) {
        int n = n4 * 4 + g;
        float a = rain[n * rstride] * Wr[j];
        float b = 0.f;
#pragma unroll
        for (int k = 0; k < 64; ++k) {
            float xk = h[n * 64 + k];
            a = fmaf(xk, sWs[k * 16 + j], a);
            b = fmaf(xk, sWd[k * 16 + j], b);
        }
        Ap[n * 16 + j] = a;
        Bp[n * 16 + j] = b;
    }
}

// ---- Pe = p @ Wp_e[s]   [N,16]@[16,16] ----
__global__ void pe16_kernel(const float* __restrict__ p, const float* __restrict__ We,
                            float* __restrict__ Pe) {
    __shared__ float sW[256];
    if (threadIdx.x < 256) sW[threadIdx.x] = We[threadIdx.x];
    __syncthreads();
    int i = blockIdx.x * blockDim.x + threadIdx.x;
    if (i >= NN * 16) return;
    int n = i >> 4, j = i & 15;
    float acc = 0.f;
#pragma unroll
    for (int k = 0; k < 16; ++k) acc = fmaf(p[n * 16 + k], sW[k * 16 + j], acc);
    Pe[i] = acc;
}

// ---- edge pass, 64-wide: agg[dst] += relu(A[src] + B[dst] + ef@We). Wave per edge.
__global__ void edge64_kernel(const float* __restrict__ A, const float* __restrict__ B,
                              const float* __restrict__ ef, const float* __restrict__ We,
                              const int* __restrict__ src, const int* __restrict__ dst,
                              float* __restrict__ agg) {
    __shared__ float sWe[512];
    for (int i = threadIdx.x; i < 512; i += blockDim.x) sWe[i] = We[i];
    __syncthreads();
    int lane = threadIdx.x & 63;
    int wid = (blockIdx.x * blockDim.x + threadIdx.x) >> 6;
    int nw = (gridDim.x * blockDim.x) >> 6;
    for (int e = wid; e < NE; e += nw) {
        int s = src[e], d = dst[e];
        const float4* e4 = reinterpret_cast<const float4*>(ef + e * 8);
        float4 f0 = e4[0], f1 = e4[1];
        float m = A[s * 64 + lane] + B[d * 64 + lane];
        m = fmaf(f0.x, sWe[0 * 64 + lane], m);
        m = fmaf(f0.y, sWe[1 * 64 + lane], m);
        m = fmaf(f0.z, sWe[2 * 64 + lane], m);
        m = fmaf(f0.w, sWe[3 * 64 + lane], m);
        m = fmaf(f1.x, sWe[4 * 64 + lane], m);
        m = fmaf(f1.y, sWe[5 * 64 + lane], m);
        m = fmaf(f1.z, sWe[6 * 64 + lane], m);
        m = fmaf(f1.w, sWe[7 * 64 + lane], m);
        m = fmaxf(m, 0.f);
        atomicAdd(&agg[d * 64 + lane], m);
    }
}

// ---- edge pass, 16-wide, edge-feature variant (first prop): uses ef @ Wfold ----
__global__ void edge16_ef_kernel(const float* __restrict__ Ap, const float* __restrict__ Bp,
                                 const float* __restrict__ ef, const float* __restrict__ Wf,
                                 const int* __restrict__ src, const int* __restrict__ dst,
                                 float* __restrict__ aggp) {
    __shared__ float sW[128];
    if (threadIdx.x < 128) sW[threadIdx.x] = Wf[threadIdx.x];
    __syncthreads();
    int lane = threadIdx.x & 63;
    int g = lane >> 4, j = lane & 15;
    int wid = (blockIdx.x * blockDim.x + threadIdx.x) >> 6;
    int nw = (gridDim.x * blockDim.x) >> 6;
    for (int e4i = wid; e4i < NE / 4; e4i += nw) {
        int e = e4i * 4 + g;
        int s = src[e], d = dst[e];
        float m = Ap[s * 16 + j] + Bp[d * 16 + j];
#pragma unroll
        for (int k = 0; k < 8; ++k) m = fmaf(ef[e * 8 + k], sW[k * 16 + j], m);
        m = fmaxf(m, 0.f);
        atomicAdd(&aggp[d * 16 + j], m);
    }
}

// ---- edge pass, 16-wide, node-feature variant: uses Pe[src] ----
__global__ void edge16_pe_kernel(const float* __restrict__ Ap, const float* __restrict__ Bp,
                                 const float* __restrict__ Pe,
                                 const int* __restrict__ src, const int* __restrict__ dst,
                                 float* __restrict__ aggp) {
    int lane = threadIdx.x & 63;
    int g = lane >> 4, j = lane & 15;
    int wid = (blockIdx.x * blockDim.x + threadIdx.x) >> 6;
    int nw = (gridDim.x * blockDim.x) >> 6;
    for (int e4i = wid; e4i < NE / 4; e4i += nw) {
        int e = e4i * 4 + g;
        int s = src[e], d = dst[e];
        float m = Ap[s * 16 + j] + Bp[d * 16 + j] + Pe[s * 16 + j];
        m = fmaxf(m, 0.f);
        atomicAdd(&aggp[d * 16 + j], m);
    }
}

// ---- h = relu(agg) ----
__global__ void relu_kernel(const float* __restrict__ in, float* __restrict__ out, int n) {
    int i = blockIdx.x * blockDim.x + threadIdx.x;
    if (i < n) out[i] = fmaxf(in[i], 0.f);
}

// ---- out layer finish: h = relu(agg); out[n,t] = h[n,:] . W_rain ----
__global__ void out_finish_kernel(const float* __restrict__ agg, const float* __restrict__ Wr,
                                  float* __restrict__ h, float* __restrict__ out, int t) {
    int lane = threadIdx.x & 63;
    int wid = (blockIdx.x * blockDim.x + threadIdx.x) >> 6;
    int nw = (gridDim.x * blockDim.x) >> 6;
    for (int n = wid; n < NN; n += nw) {
        float v = fmaxf(agg[n * 64 + lane], 0.f);
        h[n * 64 + lane] = v;
        float r = v * Wr[lane];
#pragma unroll
        for (int off = 32; off > 0; off >>= 1) r += __shfl_down(r, off);
        if (lane == 0) out[n * TT + t] = r;
    }
}

extern "C" void kernel_launch(void* const* d_in, const int* in_sizes, int n_in,
                              void* d_out, int out_size, void* d_ws, size_t ws_size,
                              hipStream_t stream) {
    const float* inputs = (const float*)d_in[0];
    const float* e_feats = (const float*)d_in[1];
    const float* rain0 = (const float*)d_in[2];
    const int* src = (const int*)d_in[3];
    const int* dst = (const int*)d_in[4];
    const float* W_emb = (const float*)d_in[5];
    const float* Win_hs = (const float*)d_in[6];
    const float* Win_hd = (const float*)d_in[7];
    const float* Win_e = (const float*)d_in[8];
    const float* Win_r = (const float*)d_in[9];
    const float* Wp_hs = (const float*)d_in[10];
    const float* Wp_hd = (const float*)d_in[11];
    const float* Wp_e = (const float*)d_in[12];
    const float* Wp_r = (const float*)d_in[13];
    const float* Wo_hs = (const float*)d_in[14];
    const float* Wo_hd = (const float*)d_in[15];
    const float* Wo_e = (const float*)d_in[16];
    const float* Wo_r = (const float*)d_in[17];
    const float* W_rain = (const float*)d_in[18];
    float* out = (float*)d_out;

    float* ws = (float*)d_ws;
    float* h = ws;      ws += NN * HD;
    float* A = ws;      ws += NN * HD;
    float* B = ws;      ws += NN * HD;
    float* agg = ws;    ws += NN * HD;
    float* p0 = ws;     ws += NN * DC;
    float* p1 = ws;     ws += NN * DC;
    float* Ap = ws;     ws += NN * DC;
    float* Bp = ws;     ws += NN * DC;
    float* Pe = ws;     ws += NN * DC;
    float* efb = ws;    ws += NE * 8;
    float* Wfold = ws;  ws += 128;

    dim3 blk(256);

    emb_kernel<<<(NN * HD + 255) / 256, blk, 0, stream>>>(inputs, W_emb, h);
    wfold_kernel<<<1, 128, 0, stream>>>(Wp_e, Wfold);

    for (int t = 0; t < TT; ++t) {
        const float* rain = rain0 + t;  // stride TT
        gather_ef_kernel<<<(NE * 8 + 255) / 256, blk, 0, stream>>>(e_feats, t, efb);

        // ---- IN layers (s = 0, 1) ----
        for (int s = 0; s < 2; ++s) {
            node_ab_kernel<<<1024, blk, 64 * 64 * 2 * sizeof(float), stream>>>(
                h, nullptr, 0, Win_hs + s * 4096, Win_hd + s * 4096, rain, TT,
                Win_r + s * 64, A, B);
            hipMemsetAsync(agg, 0, NN * HD * sizeof(float), stream);
            edge64_kernel<<<2048, blk, 0, stream>>>(A, B, efb, Win_e + s * 512, src, dst, agg);
            relu_kernel<<<(NN * HD + 255) / 256, blk, 0, stream>>>(agg, h, NN * HD);
        }

        // ---- PROP first call (s=0, edge-level ef tiled -> folded weights) ----
        node_ab16_kernel<<<1024, blk, 0, stream>>>(h, Wp_hs, Wp_hd, rain, TT, Wp_r, Ap, Bp);
        hipMemsetAsync(p0, 0, NN * DC * sizeof(float), stream);
        edge16_ef_kernel<<<1024, blk, 0, stream>>>(Ap, Bp, efb, Wfold, src, dst, p0);

        float* pc = p0;
        float* pn = p1;
        int sstart = (t == 0) ? 0 : 1;
        for (int s = sstart; s < 2; ++s) {
            if (s != 0) {
                node_ab16_kernel<<<1024, blk, 0, stream>>>(
                    h, Wp_hs + s * 1024, Wp_hd + s * 1024, rain, TT, Wp_r + s * 16, Ap, Bp);
            }
            pe16_kernel<<<(NN * DC + 255) / 256, blk, 0, stream>>>(pc, Wp_e + s * 256, Pe);
            hipMemsetAsync(pn, 0, NN * DC * sizeof(float), stream);
            edge16_pe_kernel<<<1024, blk, 0, stream>>>(Ap, Bp, Pe, src, dst, pn);
            float* tmp = pc; pc = pn; pn = tmp;
        }

        // ---- OUT layer (input concat(h, p) -> split weight blocks) ----
        node_ab_kernel<<<1024, blk, 80 * 64 * 2 * sizeof(float), stream>>>(
            h, pc, 16, Wo_hs, Wo_hd, rain, TT, Wo_r, A, B);
        hipMemsetAsync(agg, 0, NN * HD * sizeof(float), stream);
        edge64_kernel<<<2048, blk, 0, stream>>>(A, B, efb, Wo_e, src, dst, agg);
        out_finish_kernel<<<2048, blk, 0, stream>>>(agg, W_rain, h, out, t);
    }
}

// Round 2
// 1624.962 us; speedup vs baseline: 2.1158x; 2.1158x over previous
//
#include <hip/hip_runtime.h>

#define NN 40000
#define NE 320000
#define TT 4

__device__ __forceinline__ float bcast(float v, int k) {
    return __builtin_bit_cast(float, __builtin_amdgcn_readlane(__builtin_bit_cast(int, v), k));
}

// ---------------- embedding: h = inputs @ W_emb  [N,16]@[16,64] ----------------
__global__ void emb_kernel(const float* __restrict__ x, const float* __restrict__ W,
                           float* __restrict__ h) {
    int i = blockIdx.x * blockDim.x + threadIdx.x;
    if (i >= NN * 64) return;
    int n = i >> 6, j = i & 63;
    float acc = 0.f;
#pragma unroll
    for (int k = 0; k < 16; ++k) acc = fmaf(x[n * 16 + k], W[k * 64 + j], acc);
    h[i] = acc;
}

// -------- gather e_feats[:,:,t] for ALL t at once: contiguous float4 reads --------
__global__ void gather_ef_all(const float* __restrict__ ef, float* __restrict__ out) {
    int i = blockIdx.x * blockDim.x + threadIdx.x;
    if (i >= NE * 8) return;
    float4 v = reinterpret_cast<const float4*>(ef)[i];
    out[i] = v.x;
    out[NE * 8 + i] = v.y;
    out[2 * NE * 8 + i] = v.z;
    out[3 * NE * 8 + i] = v.w;
}

__global__ void gather_ef_one(const float* __restrict__ ef, int t, float* __restrict__ out) {
    int i = blockIdx.x * blockDim.x + threadIdx.x;
    if (i < NE * 8) out[i] = ef[i * 4 + t];
}

// ---- Wfold[k][j] = Wp_e[0][k][j] + Wp_e[0][k+8][j]  (folds tile(ef,(1,2))) ----
__global__ void wfold_kernel(const float* __restrict__ We, float* __restrict__ Wf) {
    int i = threadIdx.x;
    if (i < 128) Wf[i] = We[i] + We[i + 128];
}

// ---- node transform 64-wide: A = relu?(X1)@Whs (+X2@Whs[64:]) + rain*Wr, B likewise.
// 16 nodes per wave, readlane broadcast, weights in LDS. Grid must be 625 blocks.
__global__ __launch_bounds__(256) void node_ab_kernel(
    const float* __restrict__ X1, int relu1,
    const float* __restrict__ X2, int d2,
    const float* __restrict__ Whs, const float* __restrict__ Whd,
    const float* __restrict__ rain, const float* __restrict__ Wr,
    float* __restrict__ A, float* __restrict__ B) {
    extern __shared__ float sW[];
    const int dtot = 64 + d2;
    float* sWs = sW;
    float* sWd = sW + (dtot << 6);
    for (int i = threadIdx.x; i < (dtot << 6); i += 256) {
        sWs[i] = Whs[i];
        sWd[i] = Whd[i];
    }
    __syncthreads();
    const int lane = threadIdx.x & 63;
    const int wid = (blockIdx.x << 2) + (threadIdx.x >> 6);
    const int n0 = wid << 4;  // 16 nodes per wave
    const float wr = Wr[lane];
    float xv[16], aa[16], bb[16];
#pragma unroll
    for (int p = 0; p < 16; ++p) {
        float x = X1[(n0 + p) * 64 + lane];
        xv[p] = relu1 ? fmaxf(x, 0.f) : x;
        aa[p] = rain[(n0 + p) * TT] * wr;
        bb[p] = 0.f;
    }
#pragma unroll 16
    for (int k = 0; k < 64; ++k) {
        float ws = sWs[(k << 6) + lane];
        float wd = sWd[(k << 6) + lane];
#pragma unroll
        for (int p = 0; p < 16; ++p) {
            float xk = bcast(xv[p], k);
            aa[p] = fmaf(xk, ws, aa[p]);
            bb[p] = fmaf(xk, wd, bb[p]);
        }
    }
    if (d2) {
#pragma unroll
        for (int p = 0; p < 16; ++p) xv[p] = X2[(n0 + p) * 16 + (lane & 15)];
#pragma unroll
        for (int k = 0; k < 16; ++k) {
            float ws = sWs[((64 + k) << 6) + lane];
            float wd = sWd[((64 + k) << 6) + lane];
#pragma unroll
            for (int p = 0; p < 16; ++p) {
                float xk = bcast(xv[p], k);
                aa[p] = fmaf(xk, ws, aa[p]);
                bb[p] = fmaf(xk, wd, bb[p]);
            }
        }
    }
#pragma unroll
    for (int p = 0; p < 16; ++p) {
        A[(n0 + p) * 64 + lane] = aa[p];
        B[(n0 + p) * 64 + lane] = bb[p];
    }
}

// ---- fused prop node transform (16-wide out):
//   Ap = relu(X)@Whs + rain*Wr + [P@We], Bp = relu(X)@Whd
// Block stages a 64-node X tile in LDS (padded stride 68). Grid must be 625 blocks.
__global__ __launch_bounds__(256) void node_p_kernel(
    const float* __restrict__ X, const float* __restrict__ P, int has_p,
    const float* __restrict__ Whs, const float* __restrict__ Whd,
    const float* __restrict__ We,
    const float* __restrict__ rain, const float* __restrict__ Wr,
    float* __restrict__ Ap, float* __restrict__ Bp) {
    __shared__ float sX[64 * 68];
    __shared__ float sP[64 * 20];
    __shared__ float sWs[1024], sWd[1024], sWe[256];
    for (int i = threadIdx.x; i < 1024; i += 256) {
        sWs[i] = Whs[i];
        sWd[i] = Whd[i];
    }
    sWe[threadIdx.x] = has_p ? We[threadIdx.x] : 0.f;
    const int n0 = blockIdx.x << 6;  // 64 nodes per block
    for (int i = threadIdx.x; i < 1024; i += 256) {
        int row = i >> 4, col = (i & 15) << 2;
        const float4 v = *reinterpret_cast<const float4*>(&X[(n0 + row) * 64 + col]);
        float* d = &sX[row * 68 + col];
        d[0] = fmaxf(v.x, 0.f);
        d[1] = fmaxf(v.y, 0.f);
        d[2] = fmaxf(v.z, 0.f);
        d[3] = fmaxf(v.w, 0.f);
    }
    if (has_p) {
        int row = threadIdx.x >> 2, col = (threadIdx.x & 3) << 2;
        const float4 v = *reinterpret_cast<const float4*>(&P[(n0 + row) * 16 + col]);
        float* d = &sP[row * 20 + col];
        d[0] = v.x; d[1] = v.y; d[2] = v.z; d[3] = v.w;
    }
    __syncthreads();
    const int j = threadIdx.x & 15;
    const int nl0 = threadIdx.x >> 4;  // 0..15
    const float wr = Wr[j];
    float a[4], b[4];
#pragma unroll
    for (int q = 0; q < 4; ++q) {
        int n = n0 + nl0 + (q << 4);
        a[q] = rain[n * TT] * wr;
        b[q] = 0.f;
    }
#pragma unroll 8
    for (int k = 0; k < 64; ++k) {
        float wa = sWs[(k << 4) + j];
        float wb = sWd[(k << 4) + j];
#pragma unroll
        for (int q = 0; q < 4; ++q) {
            float x = sX[(nl0 + (q << 4)) * 68 + k];
            a[q] = fmaf(x, wa, a[q]);
            b[q] = fmaf(x, wb, b[q]);
        }
    }
    if (has_p) {
#pragma unroll
        for (int k = 0; k < 16; ++k) {
            float wa = sWe[(k << 4) + j];
#pragma unroll
            for (int q = 0; q < 4; ++q) {
                float x = sP[(nl0 + (q << 4)) * 20 + k];
                a[q] = fmaf(x, wa, a[q]);
            }
        }
    }
#pragma unroll
    for (int q = 0; q < 4; ++q) {
        int n = n0 + nl0 + (q << 4);
        Ap[n * 16 + j] = a[q];
        Bp[n * 16 + j] = b[q];
    }
}

// ---- edge pass 64-wide: agg[dst] += relu(A[src] + B[dst] + ef@We). Wave per edge.
__global__ void edge64_kernel(const float* __restrict__ A, const float* __restrict__ B,
                              const float* __restrict__ ef, const float* __restrict__ We,
                              const int* __restrict__ src, const int* __restrict__ dst,
                              float* __restrict__ agg) {
    __shared__ float sWe[512];
    for (int i = threadIdx.x; i < 512; i += blockDim.x) sWe[i] = We[i];
    __syncthreads();
    int lane = threadIdx.x & 63;
    int wid = (blockIdx.x * blockDim.x + threadIdx.x) >> 6;
    int nw = (gridDim.x * blockDim.x) >> 6;
    for (int e = wid; e < NE; e += nw) {
        int s = src[e], d = dst[e];
        const float4* e4 = reinterpret_cast<const float4*>(ef + e * 8);
        float4 f0 = e4[0], f1 = e4[1];
        float m = A[s * 64 + lane] + B[d * 64 + lane];
        m = fmaf(f0.x, sWe[0 * 64 + lane], m);
        m = fmaf(f0.y, sWe[1 * 64 + lane], m);
        m = fmaf(f0.z, sWe[2 * 64 + lane], m);
        m = fmaf(f0.w, sWe[3 * 64 + lane], m);
        m = fmaf(f1.x, sWe[4 * 64 + lane], m);
        m = fmaf(f1.y, sWe[5 * 64 + lane], m);
        m = fmaf(f1.z, sWe[6 * 64 + lane], m);
        m = fmaf(f1.w, sWe[7 * 64 + lane], m);
        m = fmaxf(m, 0.f);
        atomicAdd(&agg[d * 64 + lane], m);
    }
}

// ---- edge pass 16-wide, edge-feature variant (first prop): ef @ Wfold ----
__global__ void edge16_ef_kernel(const float* __restrict__ Ap, const float* __restrict__ Bp,
                                 const float* __restrict__ ef, const float* __restrict__ Wf,
                                 const int* __restrict__ src, const int* __restrict__ dst,
                                 float* __restrict__ aggp) {
    __shared__ float sW[128];
    if (threadIdx.x < 128) sW[threadIdx.x] = Wf[threadIdx.x];
    __syncthreads();
    int lane = threadIdx.x & 63;
    int g = lane >> 4, j = lane & 15;
    int wid = (blockIdx.x * blockDim.x + threadIdx.x) >> 6;
    int nw = (gridDim.x * blockDim.x) >> 6;
    for (int e4i = wid; e4i < NE / 4; e4i += nw) {
        int e = e4i * 4 + g;
        int s = src[e], d = dst[e];
        float m = Ap[s * 16 + j] + Bp[d * 16 + j];
#pragma unroll
        for (int k = 0; k < 8; ++k) m = fmaf(ef[e * 8 + k], sW[k * 16 + j], m);
        m = fmaxf(m, 0.f);
        atomicAdd(&aggp[d * 16 + j], m);
    }
}

// ---- edge pass 16-wide: p-term already folded into Ap ----
__global__ void edge16_pe_kernel(const float* __restrict__ Ap, const float* __restrict__ Bp,
                                 const int* __restrict__ src, const int* __restrict__ dst,
                                 float* __restrict__ aggp) {
    int lane = threadIdx.x & 63;
    int g = lane >> 4, j = lane & 15;
    int wid = (blockIdx.x * blockDim.x + threadIdx.x) >> 6;
    int nw = (gridDim.x * blockDim.x) >> 6;
    for (int e4i = wid; e4i < NE / 4; e4i += nw) {
        int e = e4i * 4 + g;
        int s = src[e], d = dst[e];
        float m = Ap[s * 16 + j] + Bp[d * 16 + j];
        m = fmaxf(m, 0.f);
        atomicAdd(&aggp[d * 16 + j], m);
    }
}

// ---- out[n,t] = relu(agg[n,:]) . W_rain ----
__global__ void outdot_kernel(const float* __restrict__ agg, const float* __restrict__ Wr,
                              float* __restrict__ out, int t) {
    int lane = threadIdx.x & 63;
    float w = Wr[lane];
    int wid = (blockIdx.x * blockDim.x + threadIdx.x) >> 6;
    int nw = (gridDim.x * blockDim.x) >> 6;
    for (int n = wid; n < NN; n += nw) {
        float r = fmaxf(agg[n * 64 + lane], 0.f) * w;
#pragma unroll
        for (int off = 32; off > 0; off >>= 1) r += __shfl_down(r, off);
        if (lane == 0) out[n * TT + t] = r;
    }
}

extern "C" void kernel_launch(void* const* d_in, const int* in_sizes, int n_in,
                              void* d_out, int out_size, void* d_ws, size_t ws_size,
                              hipStream_t stream) {
    (void)in_sizes; (void)n_in; (void)out_size;
    const float* inputs = (const float*)d_in[0];
    const float* e_feats = (const float*)d_in[1];
    const float* rain0 = (const float*)d_in[2];
    const int* src = (const int*)d_in[3];
    const int* dst = (const int*)d_in[4];
    const float* W_emb = (const float*)d_in[5];
    const float* Win_hs = (const float*)d_in[6];
    const float* Win_hd = (const float*)d_in[7];
    const float* Win_e = (const float*)d_in[8];
    const float* Win_r = (const float*)d_in[9];
    const float* Wp_hs = (const float*)d_in[10];
    const float* Wp_hd = (const float*)d_in[11];
    const float* Wp_e = (const float*)d_in[12];
    const float* Wp_r = (const float*)d_in[13];
    const float* Wo_hs = (const float*)d_in[14];
    const float* Wo_hd = (const float*)d_in[15];
    const float* Wo_e = (const float*)d_in[16];
    const float* Wo_r = (const float*)d_in[17];
    const float* W_rain = (const float*)d_in[18];
    float* out = (float*)d_out;

    const size_t NF64 = (size_t)NN * 64;   // 2.56M floats
    const size_t NF16 = (size_t)NN * 16;   // 640K floats
    const size_t EF = (size_t)NE * 8;      // 2.56M floats

    float* ws = (float*)d_ws;
    const size_t need_big = (6 * NF64 + 4 * NF16 + 4 * EF + 256) * sizeof(float);
    const bool big = ws_size >= need_big;

    float *A, *B, *aggA, *aggB, *aggO, *hemb, *p0, *p1, *Ap, *Bp, *efbase, *Wfold;
    if (big) {
        A = ws;      ws += NF64;
        B = ws;      ws += NF64;
        aggA = ws;   ws += NF64;
        aggB = ws;   ws += NF64;
        aggO = ws;   ws += NF64;
        hemb = ws;   ws += NF64;
        p0 = ws;     ws += NF16;
        p1 = ws;     ws += NF16;
        Ap = ws;     ws += NF16;
        Bp = ws;     ws += NF16;
        efbase = ws; ws += 4 * EF;
        Wfold = ws;
    } else {
        // aliased layout (<= ~61.5 MB), proven safe ordering:
        //  Ap/Bp live inside A (dead between OUT write and next read),
        //  p0/p1 live inside aggA (dead after IN s=1 consumes it),
        //  hemb aliases aggO (only needed before first OUT write).
        A = ws;      ws += NF64;
        B = ws;      ws += NF64;
        aggA = ws;   ws += NF64;
        aggB = ws;   ws += NF64;
        aggO = ws;   ws += NF64;
        efbase = ws; ws += EF;
        Wfold = ws;
        hemb = aggO;
        Ap = A;
        Bp = A + NF16;
        p0 = aggA;
        p1 = aggA + NF16;
    }

    emb_kernel<<<(NN * 64 + 255) / 256, 256, 0, stream>>>(inputs, W_emb, hemb);
    wfold_kernel<<<1, 128, 0, stream>>>(Wp_e, Wfold);
    if (big)
        gather_ef_all<<<(NE * 8 + 255) / 256, 256, 0, stream>>>(e_feats, efbase);

    for (int t = 0; t < TT; ++t) {
        const float* rain = rain0 + t;
        float* eft = big ? (efbase + (size_t)t * EF) : efbase;
        if (!big)
            gather_ef_one<<<(NE * 8 + 255) / 256, 256, 0, stream>>>(e_feats, t, efbase);

        // ---- IN s=0 ----
        node_ab_kernel<<<625, 256, 64 * 64 * 2 * sizeof(float), stream>>>(
            (t == 0) ? hemb : aggO, (t > 0) ? 1 : 0, nullptr, 0,
            Win_hs, Win_hd, rain, Win_r, A, B);
        hipMemsetAsync(aggA, 0, NF64 * sizeof(float), stream);
        edge64_kernel<<<2048, 256, 0, stream>>>(A, B, eft, Win_e, src, dst, aggA);

        // ---- IN s=1 ----
        node_ab_kernel<<<625, 256, 64 * 64 * 2 * sizeof(float), stream>>>(
            aggA, 1, nullptr, 0, Win_hs + 4096, Win_hd + 4096, rain, Win_r + 64, A, B);
        hipMemsetAsync(aggB, 0, NF64 * sizeof(float), stream);
        edge64_kernel<<<2048, 256, 0, stream>>>(A, B, eft, Win_e + 512, src, dst, aggB);

        // ---- PROP first call (s=0, edge-level ef with folded weights) ----
        node_p_kernel<<<625, 256, 0, stream>>>(aggB, nullptr, 0, Wp_hs, Wp_hd, nullptr,
                                               rain, Wp_r, Ap, Bp);
        hipMemsetAsync(p0, 0, NF16 * sizeof(float), stream);
        edge16_ef_kernel<<<1024, 256, 0, stream>>>(Ap, Bp, eft, Wfold, src, dst, p0);

        float* pc = p0;
        float* pn = p1;
        for (int s = (t == 0) ? 0 : 1; s < 2; ++s) {
            node_p_kernel<<<625, 256, 0, stream>>>(aggB, pc, 1, Wp_hs + s * 1024,
                                                   Wp_hd + s * 1024, Wp_e + s * 256,
                                                   rain, Wp_r + s * 16, Ap, Bp);
            hipMemsetAsync(pn, 0, NF16 * sizeof(float), stream);
            edge16_pe_kernel<<<1024, 256, 0, stream>>>(Ap, Bp, src, dst, pn);
            float* tmp = pc; pc = pn; pn = tmp;
        }

        // ---- OUT layer ----
        node_ab_kernel<<<625, 256, 80 * 64 * 2 * sizeof(float), stream>>>(
            aggB, 1, pc, 16, Wo_hs, Wo_hd, rain, Wo_r, A, B);
        hipMemsetAsync(aggO, 0, NF64 * sizeof(float), stream);
        edge64_kernel<<<2048, 256, 0, stream>>>(A, B, eft, Wo_e, src, dst, aggO);
        outdot_kernel<<<1024, 256, 0, stream>>>(aggO, W_rain, out, t);
    }
}

// Round 3
// 1250.266 us; speedup vs baseline: 2.7498x; 1.2997x over previous
//
#include <hip/hip_runtime.h>

#define NN 40000
#define NE 320000
#define TT 4
#define SCAN_CHUNK 1024
#define NBLK_SCAN ((NN + SCAN_CHUNK - 1) / SCAN_CHUNK)  // 40

__device__ __forceinline__ float bcast(float v, int k) {
    return __builtin_bit_cast(float, __builtin_amdgcn_readlane(__builtin_bit_cast(int, v), k));
}

// ---------------- embedding: h = inputs @ W_emb  [N,16]@[16,64] ----------------
__global__ void emb_kernel(const float* __restrict__ x, const float* __restrict__ W,
                           float* __restrict__ h) {
    int i = blockIdx.x * blockDim.x + threadIdx.x;
    if (i >= NN * 64) return;
    int n = i >> 6, j = i & 63;
    float acc = 0.f;
#pragma unroll
    for (int k = 0; k < 16; ++k) acc = fmaf(x[n * 16 + k], W[k * 64 + j], acc);
    h[i] = acc;
}

// ---- Wfold[k][j] = Wp_e[0][k][j] + Wp_e[0][k+8][j]  (folds tile(ef,(1,2))) ----
__global__ void wfold_kernel(const float* __restrict__ We, float* __restrict__ Wf) {
    int i = threadIdx.x;
    if (i < 128) Wf[i] = We[i] + We[i + 128];
}

// ================= CSR build (once per launch) =================
__global__ void hist_kernel(const int* __restrict__ dst, int* __restrict__ deg) {
    int e = blockIdx.x * blockDim.x + threadIdx.x;
    if (e < NE) atomicAdd(&deg[dst[e]], 1);
}

__global__ void scan1_kernel(const int* __restrict__ deg, int* __restrict__ bsum) {
    __shared__ int sdata[256];
    int b = blockIdx.x, t = threadIdx.x;
    int base = b * SCAN_CHUNK;
    int sum = 0;
    for (int i = t; i < SCAN_CHUNK; i += 256) {
        int idx = base + i;
        sum += (idx < NN) ? deg[idx] : 0;
    }
    sdata[t] = sum;
    __syncthreads();
    for (int off = 128; off > 0; off >>= 1) {
        if (t < off) sdata[t] += sdata[t + off];
        __syncthreads();
    }
    if (t == 0) bsum[b] = sdata[0];
}

__global__ void scan2_kernel(const int* __restrict__ bsum, int* __restrict__ boff,
                             int* __restrict__ rowptr) {
    if (threadIdx.x == 0) {
        int acc = 0;
        for (int i = 0; i < NBLK_SCAN; ++i) {
            boff[i] = acc;
            acc += bsum[i];
        }
        rowptr[NN] = NE;
    }
}

__global__ void scan3_kernel(const int* __restrict__ deg, const int* __restrict__ boff,
                             int* __restrict__ rowptr) {
    __shared__ int ss[256];
    int b = blockIdx.x, t = threadIdx.x;
    int base = b * SCAN_CHUNK + t * 4;
    int v[4], s = 0;
#pragma unroll
    for (int q = 0; q < 4; ++q) {
        int idx = base + q;
        v[q] = (idx < NN) ? deg[idx] : 0;
        s += v[q];
    }
    ss[t] = s;
    __syncthreads();
    for (int off = 1; off < 256; off <<= 1) {
        int add = (t >= off) ? ss[t - off] : 0;
        __syncthreads();
        ss[t] += add;
        __syncthreads();
    }
    int excl = boff[b] + ss[t] - s;
#pragma unroll
    for (int q = 0; q < 4; ++q) {
        int idx = base + q;
        if (idx < NN) rowptr[idx] = excl;
        excl += v[q];
    }
}

__global__ void scatter_kernel(const int* __restrict__ src, const int* __restrict__ dst,
                               int* __restrict__ cursor, int* __restrict__ perm,
                               int* __restrict__ srcp) {
    int e = blockIdx.x * blockDim.x + threadIdx.x;
    if (e >= NE) return;
    int d = dst[e];
    int pos = atomicAdd(&cursor[d], 1);
    perm[pos] = e;
    srcp[pos] = src[e];
}

// -------- permute e_feats into CSR order; all 4 timestep planes at once --------
__global__ void efperm_all_kernel(const float* __restrict__ ef, const int* __restrict__ perm,
                                  float* __restrict__ out) {
    int pos = blockIdx.x * blockDim.x + threadIdx.x;
    if (pos >= NE) return;
    int e = perm[pos];
    const float4* e4 = reinterpret_cast<const float4*>(ef) + (size_t)e * 8;
#pragma unroll
    for (int k = 0; k < 8; ++k) {
        float4 v = e4[k];
        out[0 * (size_t)NE * 8 + pos * 8 + k] = v.x;
        out[1 * (size_t)NE * 8 + pos * 8 + k] = v.y;
        out[2 * (size_t)NE * 8 + pos * 8 + k] = v.z;
        out[3 * (size_t)NE * 8 + pos * 8 + k] = v.w;
    }
}

// -------- permute e_feats into CSR order, single timestep (small-ws path) --------
__global__ void efperm_one_kernel(const float* __restrict__ ef, const int* __restrict__ perm,
                                  int t, float* __restrict__ out) {
    int i = blockIdx.x * blockDim.x + threadIdx.x;
    if (i >= NE * 8) return;
    int pos = i >> 3, k = i & 7;
    int e = perm[pos];
    out[i] = ef[((size_t)e * 8 + k) * 4 + t];
}

// ================= node transforms (unchanged structure) =================
// 64-wide: A = relu?(X1)@Whs (+X2@Whs[64:]) + rain*Wr, B likewise. 625 blocks.
__global__ __launch_bounds__(256) void node_ab_kernel(
    const float* __restrict__ X1, int relu1,
    const float* __restrict__ X2, int d2,
    const float* __restrict__ Whs, const float* __restrict__ Whd,
    const float* __restrict__ rain, const float* __restrict__ Wr,
    float* __restrict__ A, float* __restrict__ B) {
    extern __shared__ float sW[];
    const int dtot = 64 + d2;
    float* sWs = sW;
    float* sWd = sW + (dtot << 6);
    for (int i = threadIdx.x; i < (dtot << 6); i += 256) {
        sWs[i] = Whs[i];
        sWd[i] = Whd[i];
    }
    __syncthreads();
    const int lane = threadIdx.x & 63;
    const int wid = (blockIdx.x << 2) + (threadIdx.x >> 6);
    const int n0 = wid << 4;
    const float wr = Wr[lane];
    float xv[16], aa[16], bb[16];
#pragma unroll
    for (int p = 0; p < 16; ++p) {
        float x = X1[(n0 + p) * 64 + lane];
        xv[p] = relu1 ? fmaxf(x, 0.f) : x;
        aa[p] = rain[(n0 + p) * TT] * wr;
        bb[p] = 0.f;
    }
#pragma unroll 16
    for (int k = 0; k < 64; ++k) {
        float ws = sWs[(k << 6) + lane];
        float wd = sWd[(k << 6) + lane];
#pragma unroll
        for (int p = 0; p < 16; ++p) {
            float xk = bcast(xv[p], k);
            aa[p] = fmaf(xk, ws, aa[p]);
            bb[p] = fmaf(xk, wd, bb[p]);
        }
    }
    if (d2) {
#pragma unroll
        for (int p = 0; p < 16; ++p) xv[p] = X2[(n0 + p) * 16 + (lane & 15)];
#pragma unroll
        for (int k = 0; k < 16; ++k) {
            float ws = sWs[((64 + k) << 6) + lane];
            float wd = sWd[((64 + k) << 6) + lane];
#pragma unroll
            for (int p = 0; p < 16; ++p) {
                float xk = bcast(xv[p], k);
                aa[p] = fmaf(xk, ws, aa[p]);
                bb[p] = fmaf(xk, wd, bb[p]);
            }
        }
    }
#pragma unroll
    for (int p = 0; p < 16; ++p) {
        A[(n0 + p) * 64 + lane] = aa[p];
        B[(n0 + p) * 64 + lane] = bb[p];
    }
}

// fused prop node transform (16-wide out). 625 blocks.
__global__ __launch_bounds__(256) void node_p_kernel(
    const float* __restrict__ X, const float* __restrict__ P, int has_p,
    const float* __restrict__ Whs, const float* __restrict__ Whd,
    const float* __restrict__ We,
    const float* __restrict__ rain, const float* __restrict__ Wr,
    float* __restrict__ Ap, float* __restrict__ Bp) {
    __shared__ float sX[64 * 68];
    __shared__ float sP[64 * 20];
    __shared__ float sWs[1024], sWd[1024], sWe[256];
    for (int i = threadIdx.x; i < 1024; i += 256) {
        sWs[i] = Whs[i];
        sWd[i] = Whd[i];
    }
    sWe[threadIdx.x] = has_p ? We[threadIdx.x] : 0.f;
    const int n0 = blockIdx.x << 6;
    for (int i = threadIdx.x; i < 1024; i += 256) {
        int row = i >> 4, col = (i & 15) << 2;
        const float4 v = *reinterpret_cast<const float4*>(&X[(n0 + row) * 64 + col]);
        float* d = &sX[row * 68 + col];
        d[0] = fmaxf(v.x, 0.f);
        d[1] = fmaxf(v.y, 0.f);
        d[2] = fmaxf(v.z, 0.f);
        d[3] = fmaxf(v.w, 0.f);
    }
    if (has_p) {
        int row = threadIdx.x >> 2, col = (threadIdx.x & 3) << 2;
        const float4 v = *reinterpret_cast<const float4*>(&P[(n0 + row) * 16 + col]);
        float* d = &sP[row * 20 + col];
        d[0] = v.x; d[1] = v.y; d[2] = v.z; d[3] = v.w;
    }
    __syncthreads();
    const int j = threadIdx.x & 15;
    const int nl0 = threadIdx.x >> 4;
    const float wr = Wr[j];
    float a[4], b[4];
#pragma unroll
    for (int q = 0; q < 4; ++q) {
        int n = n0 + nl0 + (q << 4);
        a[q] = rain[n * TT] * wr;
        b[q] = 0.f;
    }
#pragma unroll 8
    for (int k = 0; k < 64; ++k) {
        float wa = sWs[(k << 4) + j];
        float wb = sWd[(k << 4) + j];
#pragma unroll
        for (int q = 0; q < 4; ++q) {
            float x = sX[(nl0 + (q << 4)) * 68 + k];
            a[q] = fmaf(x, wa, a[q]);
            b[q] = fmaf(x, wb, b[q]);
        }
    }
    if (has_p) {
#pragma unroll
        for (int k = 0; k < 16; ++k) {
            float wa = sWe[(k << 4) + j];
#pragma unroll
            for (int q = 0; q < 4; ++q) {
                float x = sP[(nl0 + (q << 4)) * 20 + k];
                a[q] = fmaf(x, wa, a[q]);
            }
        }
    }
#pragma unroll
    for (int q = 0; q < 4; ++q) {
        int n = n0 + nl0 + (q << 4);
        Ap[n * 16 + j] = a[q];
        Bp[n * 16 + j] = b[q];
    }
}

// ================= CSR edge passes: no atomics, one write per node =================
// 64-wide. Wave per dst node; optional fused rain-output epilogue. Grid = 10000.
__global__ __launch_bounds__(256) void edge64_csr(
    const float* __restrict__ A, const float* __restrict__ B,
    const float* __restrict__ efp, const float* __restrict__ We,
    const int* __restrict__ rowptr, const int* __restrict__ srcp,
    float* __restrict__ agg, const float* __restrict__ Wrain,
    float* __restrict__ out, int t) {
    __shared__ float sWe[512];
    for (int i = threadIdx.x; i < 512; i += 256) sWe[i] = We[i];
    __syncthreads();
    const int lane = threadIdx.x & 63;
    const int n = (blockIdx.x << 2) + (threadIdx.x >> 6);
    if (n >= NN) return;
    const int beg = rowptr[n], end = rowptr[n + 1];
    const float b = B[(size_t)n * 64 + lane];
    const float4* ef4 = reinterpret_cast<const float4*>(efp);
    float acc = 0.f;
    for (int pos = beg; pos < end; ++pos) {
        int s = srcp[pos];
        float4 f0 = ef4[pos * 2], f1 = ef4[pos * 2 + 1];
        float m = A[(size_t)s * 64 + lane] + b;
        m = fmaf(f0.x, sWe[0 * 64 + lane], m);
        m = fmaf(f0.y, sWe[1 * 64 + lane], m);
        m = fmaf(f0.z, sWe[2 * 64 + lane], m);
        m = fmaf(f0.w, sWe[3 * 64 + lane], m);
        m = fmaf(f1.x, sWe[4 * 64 + lane], m);
        m = fmaf(f1.y, sWe[5 * 64 + lane], m);
        m = fmaf(f1.z, sWe[6 * 64 + lane], m);
        m = fmaf(f1.w, sWe[7 * 64 + lane], m);
        acc += fmaxf(m, 0.f);
    }
    agg[(size_t)n * 64 + lane] = acc;
    if (out) {
        float r = fmaxf(acc, 0.f) * Wrain[lane];
#pragma unroll
        for (int off = 32; off > 0; off >>= 1) r += __shfl_down(r, off);
        if (lane == 0) out[n * TT + t] = r;
    }
}

// 16-wide, with edge-feature term (first prop). 4 nodes per wave. Grid = 2500.
__global__ __launch_bounds__(256) void edge16_csr_ef(
    const float* __restrict__ Ap, const float* __restrict__ Bp,
    const float* __restrict__ efp, const float* __restrict__ Wf,
    const int* __restrict__ rowptr, const int* __restrict__ srcp,
    float* __restrict__ aggp) {
    __shared__ float sW[128];
    if (threadIdx.x < 128) sW[threadIdx.x] = Wf[threadIdx.x];
    __syncthreads();
    const int lane = threadIdx.x & 63;
    const int g = lane >> 4, j = lane & 15;
    const int wid = (blockIdx.x * 256 + threadIdx.x) >> 6;
    const int n = (wid << 2) + g;
    if (n >= NN) return;
    const int beg = rowptr[n], end = rowptr[n + 1];
    const float b = Bp[n * 16 + j];
    const float4* ef4 = reinterpret_cast<const float4*>(efp);
    float acc = 0.f;
    for (int pos = beg; pos < end; ++pos) {
        int s = srcp[pos];
        float4 f0 = ef4[pos * 2], f1 = ef4[pos * 2 + 1];
        float m = Ap[s * 16 + j] + b;
        m = fmaf(f0.x, sW[0 * 16 + j], m);
        m = fmaf(f0.y, sW[1 * 16 + j], m);
        m = fmaf(f0.z, sW[2 * 16 + j], m);
        m = fmaf(f0.w, sW[3 * 16 + j], m);
        m = fmaf(f1.x, sW[4 * 16 + j], m);
        m = fmaf(f1.y, sW[5 * 16 + j], m);
        m = fmaf(f1.z, sW[6 * 16 + j], m);
        m = fmaf(f1.w, sW[7 * 16 + j], m);
        acc += fmaxf(m, 0.f);
    }
    aggp[n * 16 + j] = acc;
}

// 16-wide, p-term already folded into Ap. Grid = 2500.
__global__ __launch_bounds__(256) void edge16_csr_pe(
    const float* __restrict__ Ap, const float* __restrict__ Bp,
    const int* __restrict__ rowptr, const int* __restrict__ srcp,
    float* __restrict__ aggp) {
    const int lane = threadIdx.x & 63;
    const int g = lane >> 4, j = lane & 15;
    const int wid = (blockIdx.x * 256 + threadIdx.x) >> 6;
    const int n = (wid << 2) + g;
    if (n >= NN) return;
    const int beg = rowptr[n], end = rowptr[n + 1];
    const float b = Bp[n * 16 + j];
    float acc = 0.f;
    for (int pos = beg; pos < end; ++pos) {
        int s = srcp[pos];
        acc += fmaxf(Ap[s * 16 + j] + b, 0.f);
    }
    aggp[n * 16 + j] = acc;
}

extern "C" void kernel_launch(void* const* d_in, const int* in_sizes, int n_in,
                              void* d_out, int out_size, void* d_ws, size_t ws_size,
                              hipStream_t stream) {
    (void)in_sizes; (void)n_in; (void)out_size;
    const float* inputs = (const float*)d_in[0];
    const float* e_feats = (const float*)d_in[1];
    const float* rain0 = (const float*)d_in[2];
    const int* src = (const int*)d_in[3];
    const int* dst = (const int*)d_in[4];
    const float* W_emb = (const float*)d_in[5];
    const float* Win_hs = (const float*)d_in[6];
    const float* Win_hd = (const float*)d_in[7];
    const float* Win_e = (const float*)d_in[8];
    const float* Win_r = (const float*)d_in[9];
    const float* Wp_hs = (const float*)d_in[10];
    const float* Wp_hd = (const float*)d_in[11];
    const float* Wp_e = (const float*)d_in[12];
    const float* Wp_r = (const float*)d_in[13];
    const float* Wo_hs = (const float*)d_in[14];
    const float* Wo_hd = (const float*)d_in[15];
    const float* Wo_e = (const float*)d_in[16];
    const float* Wo_r = (const float*)d_in[17];
    const float* W_rain = (const float*)d_in[18];
    float* out = (float*)d_out;

    const size_t NF64 = (size_t)NN * 64;
    const size_t NF16 = (size_t)NN * 16;
    const size_t EF = (size_t)NE * 8;

    // int-array bytes: srcp/perm NE each, rowptr NN+1, deg/cursor NN, scan 2*64
    const size_t int_bytes = (2 * (size_t)NE + 2 * (size_t)NN + 1 + 128) * 4;
    const size_t need_big = (6 * NF64 + 4 * NF16 + 4 * EF + 128) * 4 + int_bytes;
    const bool big = ws_size >= need_big;

    float* ws = (float*)d_ws;
    float *A, *B, *aggA, *aggB, *aggO, *hemb, *p0, *p1, *Ap, *Bp, *efp, *Wfold;
    if (big) {
        A = ws;    ws += NF64;
        B = ws;    ws += NF64;
        aggA = ws; ws += NF64;
        aggB = ws; ws += NF64;
        aggO = ws; ws += NF64;
        hemb = ws; ws += NF64;
        p0 = ws;   ws += NF16;
        p1 = ws;   ws += NF16;
        Ap = ws;   ws += NF16;
        Bp = ws;   ws += NF16;
        efp = ws;  ws += 4 * EF;
        Wfold = ws; ws += 128;
    } else {
        A = ws;    ws += NF64;
        B = ws;    ws += NF64;
        aggA = ws; ws += NF64;
        aggB = ws; ws += NF64;
        aggO = ws; ws += NF64;
        efp = ws;  ws += EF;
        Wfold = ws; ws += 128;
        hemb = aggO;          // dead after first OUT write
        Ap = A;               // A/B dead while prop Ap/Bp live
        Bp = A + NF16;
        p0 = aggA;            // aggA dead after IN s=1 consumes it
        p1 = aggA + NF16;
    }
    int* ip = (int*)ws;
    int* srcp = ip;    ip += NE;
    int* perm = ip;    ip += NE;
    int* rowptr = ip;  ip += NN + 1;
    int* deg = ip;     ip += NN;       // cursor aliases deg (deg dead after scan3)
    int* bsum = ip;    ip += 64;
    int* boff = ip;    ip += 64;
    int* cursor = deg;

    // ---- CSR build (once) ----
    hipMemsetAsync(deg, 0, NN * sizeof(int), stream);
    hist_kernel<<<(NE + 255) / 256, 256, 0, stream>>>(dst, deg);
    scan1_kernel<<<NBLK_SCAN, 256, 0, stream>>>(deg, bsum);
    scan2_kernel<<<1, 64, 0, stream>>>(bsum, boff, rowptr);
    scan3_kernel<<<NBLK_SCAN, 256, 0, stream>>>(deg, boff, rowptr);
    hipMemcpyAsync(cursor, rowptr, NN * sizeof(int), hipMemcpyDeviceToDevice, stream);
    scatter_kernel<<<(NE + 255) / 256, 256, 0, stream>>>(src, dst, cursor, perm, srcp);
    if (big)
        efperm_all_kernel<<<(NE + 255) / 256, 256, 0, stream>>>(e_feats, perm, efp);

    emb_kernel<<<(NN * 64 + 255) / 256, 256, 0, stream>>>(inputs, W_emb, hemb);
    wfold_kernel<<<1, 128, 0, stream>>>(Wp_e, Wfold);

    for (int t = 0; t < TT; ++t) {
        const float* rain = rain0 + t;
        const float* eft = big ? (efp + (size_t)t * EF) : efp;
        if (!big)
            efperm_one_kernel<<<(NE * 8 + 255) / 256, 256, 0, stream>>>(e_feats, perm, t, efp);

        // ---- IN s=0 ----
        node_ab_kernel<<<625, 256, 64 * 64 * 2 * sizeof(float), stream>>>(
            (t == 0) ? hemb : aggO, (t > 0) ? 1 : 0, nullptr, 0,
            Win_hs, Win_hd, rain, Win_r, A, B);
        edge64_csr<<<10000, 256, 0, stream>>>(A, B, eft, Win_e, rowptr, srcp, aggA,
                                              nullptr, nullptr, 0);

        // ---- IN s=1 ----
        node_ab_kernel<<<625, 256, 64 * 64 * 2 * sizeof(float), stream>>>(
            aggA, 1, nullptr, 0, Win_hs + 4096, Win_hd + 4096, rain, Win_r + 64, A, B);
        edge64_csr<<<10000, 256, 0, stream>>>(A, B, eft, Win_e + 512, rowptr, srcp, aggB,
                                              nullptr, nullptr, 0);

        // ---- PROP first call (s=0, edge-level ef with folded weights) ----
        node_p_kernel<<<625, 256, 0, stream>>>(aggB, nullptr, 0, Wp_hs, Wp_hd, nullptr,
                                               rain, Wp_r, Ap, Bp);
        edge16_csr_ef<<<2500, 256, 0, stream>>>(Ap, Bp, eft, Wfold, rowptr, srcp, p0);

        float* pc = p0;
        float* pn = p1;
        for (int s = (t == 0) ? 0 : 1; s < 2; ++s) {
            node_p_kernel<<<625, 256, 0, stream>>>(aggB, pc, 1, Wp_hs + s * 1024,
                                                   Wp_hd + s * 1024, Wp_e + s * 256,
                                                   rain, Wp_r + s * 16, Ap, Bp);
            edge16_csr_pe<<<2500, 256, 0, stream>>>(Ap, Bp, rowptr, srcp, pn);
            float* tmp = pc; pc = pn; pn = tmp;
        }

        // ---- OUT layer (fused rain-output epilogue) ----
        node_ab_kernel<<<625, 256, 80 * 64 * 2 * sizeof(float), stream>>>(
            aggB, 1, pc, 16, Wo_hs, Wo_hd, rain, Wo_r, A, B);
        edge64_csr<<<10000, 256, 0, stream>>>(A, B, eft, Wo_e, rowptr, srcp, aggO,
                                              W_rain, out, t);
    }
}